// Round 2
// baseline (269.895 us; speedup 1.0000x reference)
//
#include <hip/hip_runtime.h>
#include <hip/hip_bf16.h>
#include <stdint.h>

typedef __bf16 bf16x8 __attribute__((ext_vector_type(8)));
typedef float f32x4 __attribute__((ext_vector_type(4)));
typedef unsigned short u16;
typedef u16 u16x8 __attribute__((ext_vector_type(8)));

#define GAS __attribute__((address_space(1)))
#define LAS __attribute__((address_space(3)))

static constexpr int Tn = 2048;
static constexpr int Dn = 1024;
static constexpr int Hn = 128;

__device__ __forceinline__ u16 bf16u(float f) {
  __bf16 h = (__bf16)f;
  return __builtin_bit_cast(u16, h);
}

__device__ __forceinline__ void gl_lds16(const void* g, void* l) {
  __builtin_amdgcn_global_load_lds((GAS void*)g, (LAS void*)l, 16, 0, 0);
}

// ---------------- convert + transpose weights: WT[w][h][d] bf16, Wq pre-scaled ----------------
__global__ __launch_bounds__(256) void convert_w_kernel(
    const float* __restrict__ Wq, const float* __restrict__ Wk,
    const float* __restrict__ Wv, u16* __restrict__ WT) {
  const int bid = blockIdx.x;  // 384 = 3*128
  const int w = bid >> 7;
  const int h = bid & 127;
  const float* src = (w == 0) ? Wq : ((w == 1) ? Wk : Wv);
  const float scale = (w == 0) ? 0.08838834764831845f : 1.0f;  // 1/sqrt(128) folded into Wq
  const int d0 = threadIdx.x * 4;
  ushort4 v;
  v.x = bf16u(src[(size_t)(d0 + 0) * Hn + h] * scale);
  v.y = bf16u(src[(size_t)(d0 + 1) * Hn + h] * scale);
  v.z = bf16u(src[(size_t)(d0 + 2) * Hn + h] * scale);
  v.w = bf16u(src[(size_t)(d0 + 3) * Hn + h] * scale);
  *(ushort4*)(&WT[(size_t)(w * Hn + h) * Dn + d0]) = v;
}

// ---------------- QKV projection GEMM: [16384x1024] x [1024x128] per weight ----------------
// grid 768 = 256 m-tiles(64 rows) * 3 weights; block 128 thr = 2 waves; wave tile 64x64
__global__ __launch_bounds__(128) void qkv_gemm_kernel(
    const float* __restrict__ x, const u16* __restrict__ WT,
    u16* __restrict__ qb, u16* __restrict__ kb, u16* __restrict__ vb) {
  __shared__ u16 As[64 * 64];   // [row][64 k] bf16, XOR-swizzled 16B units
  __shared__ u16 Bs[128 * 64];  // [n][64 k] bf16, XOR-swizzled (pre-swizzled global src)
  const int bid = blockIdx.x;
  const int w = bid % 3;            // 3 sibling blocks share an x-tile (L2/L3 reuse)
  const int m0 = (bid / 3) * 64;
  const int tid = threadIdx.x;
  const int lane = tid & 63;
  const int wid = tid >> 6;
  const int l15 = lane & 15;
  const int g = lane >> 4;

  const u16* wt = WT + (size_t)w * (Hn * Dn);

  const f32x4 fz = {0.f, 0.f, 0.f, 0.f};
  f32x4 acc[4][4];
#pragma unroll
  for (int i = 0; i < 4; ++i)
#pragma unroll
    for (int j = 0; j < 4; ++j) acc[i][j] = fz;

  for (int k0 = 0; k0 < Dn; k0 += 64) {
    // stage A: fp32 -> bf16 convert, XOR-swizzled LDS write
#pragma unroll
    for (int j = 0; j < 8; ++j) {
      const int s = j * 128 + tid;
      const int row = s >> 4;
      const int c16 = s & 15;  // 4-float unit within row
      const float4 fa = *(const float4*)(x + (size_t)(m0 + row) * Dn + k0 + c16 * 4);
      const int u = c16 >> 1, half = c16 & 1;
      const int slot = u ^ (row & 7);
      ushort4 pk;
      pk.x = bf16u(fa.x); pk.y = bf16u(fa.y); pk.z = bf16u(fa.z); pk.w = bf16u(fa.w);
      *(ushort4*)(&As[row * 64 + slot * 8 + half * 4]) = pk;
    }
    // stage B: global_load_lds (linear LDS dest, pre-swizzled global source)
#pragma unroll
    for (int i = 0; i < 8; ++i) {
      const int s = i * 128 + tid;
      const int n = s >> 3;
      const int us = s & 7;
      const u16* gsrc = wt + (size_t)n * Dn + k0 + ((us ^ (n & 7)) * 8);
      gl_lds16(gsrc, &Bs[(i * 128 + wid * 64) * 8]);
    }
    __syncthreads();
#pragma unroll
    for (int kc = 0; kc < 2; ++kc) {
      bf16x8 af[4], bfr[4];
#pragma unroll
      for (int mi = 0; mi < 4; ++mi) {
        const int row = mi * 16 + l15;
        af[mi] = *(const bf16x8*)(&As[row * 64 + (((kc * 4 + g) ^ (row & 7)) * 8)]);
      }
#pragma unroll
      for (int ni = 0; ni < 4; ++ni) {
        const int n = wid * 64 + ni * 16 + l15;
        bfr[ni] = *(const bf16x8*)(&Bs[n * 64 + (((kc * 4 + g) ^ (n & 7)) * 8)]);
      }
#pragma unroll
      for (int mi = 0; mi < 4; ++mi)
#pragma unroll
        for (int ni = 0; ni < 4; ++ni)
          acc[mi][ni] = __builtin_amdgcn_mfma_f32_16x16x32_bf16(af[mi], bfr[ni], acc[mi][ni], 0, 0, 0);
    }
    __syncthreads();
  }
  u16* dst = (w == 0) ? qb : ((w == 1) ? kb : vb);
#pragma unroll
  for (int mi = 0; mi < 4; ++mi)
#pragma unroll
    for (int ni = 0; ni < 4; ++ni)
#pragma unroll
      for (int r = 0; r < 4; ++r)
        dst[(size_t)(m0 + mi * 16 + g * 4 + r) * Hn + wid * 64 + ni * 16 + l15] =
            bf16u(acc[mi][ni][r]);
}

// ---------------- V transpose: vb[b][t][h] -> vt[b][h][t] ----------------
__global__ __launch_bounds__(256) void transpose_v_kernel(
    const u16* __restrict__ vb, u16* __restrict__ vt) {
  __shared__ u16 tile[64 * 64];
  const int bid = blockIdx.x;  // 512 = 8b * 32tt * 2hh
  const int b = bid >> 6;
  const int rem = bid & 63;
  const int t0 = (rem >> 1) * 64, h0 = (rem & 1) * 64;
  const int tid = threadIdx.x;
  {
    const int r = tid >> 2, cq = tid & 3;
    const u16* src = vb + (size_t)(b * Tn + t0 + r) * Hn + h0 + cq * 16;
#pragma unroll
    for (int s = 0; s < 2; ++s) {
      u16x8 v = *(const u16x8*)(src + s * 8);
      const int u = cq * 2 + s;
      *(u16x8*)(&tile[r * 64 + (u ^ (r & 7)) * 8]) = v;
    }
  }
  __syncthreads();
  {
    const int hr = tid >> 2, tg = tid & 3;
    u16 outv[16];
#pragma unroll
    for (int j = 0; j < 16; ++j) {
      const int tl = tg * 16 + j;
      outv[j] = tile[tl * 64 + (((hr >> 3) ^ (tl & 7)) * 8) + (hr & 7)];
    }
    u16* dstp = vt + (size_t)(b * Hn + h0 + hr) * Tn + t0 + tg * 16;
    *(u16x8*)(dstp) = *(const u16x8*)(&outv[0]);
    *(u16x8*)(dstp + 8) = *(const u16x8*)(&outv[8]);
  }
}

// ---------------- flash attention: 1 wave / 16 q-rows, KVB=64, K/V direct from L2 ----------------
__global__ __launch_bounds__(64) void attention_kernel(
    const u16* __restrict__ qb, const u16* __restrict__ kb,
    const u16* __restrict__ vt, float* __restrict__ out) {
  __shared__ u16 P[16 * 64];  // P round-trip buffer, XOR-swizzled
  const int bid = blockIdx.x;  // 1024 = 8 batches (bid&7 -> XCD) * 128 q-tiles
  const int b = bid & 7;
  const int t0 = (bid >> 3) * 16;
  const int lane = threadIdx.x;
  const int l15 = lane & 15;
  const int g = lane >> 4;
  const int g4 = g * 4;

  const u16* qB = qb + (size_t)b * Tn * Hn;
  const u16* kB = kb + (size_t)b * Tn * Hn;
  const u16* vB = vt + (size_t)b * Hn * Tn;

  bf16x8 qf[4];
#pragma unroll
  for (int kc = 0; kc < 4; ++kc)
    qf[kc] = *(const bf16x8*)(qB + (size_t)(t0 + l15) * Hn + kc * 32 + g * 8);

  const f32x4 fz = {0.f, 0.f, 0.f, 0.f};
  f32x4 o[8];
#pragma unroll
  for (int hc = 0; hc < 8; ++hc) o[hc] = fz;
  float m[4], lsum[4];
#pragma unroll
  for (int r = 0; r < 4; ++r) { m[r] = -__builtin_inff(); lsum[r] = 0.f; }

  for (int kv0 = 0; kv0 <= t0 + 15; kv0 += 64) {
    f32x4 S[4];
#pragma unroll
    for (int cn = 0; cn < 4; ++cn) S[cn] = fz;
#pragma unroll
    for (int cn = 0; cn < 4; ++cn) {
      const u16* krow = kB + (size_t)(kv0 + cn * 16 + l15) * Hn;
#pragma unroll
      for (int kc = 0; kc < 4; ++kc) {
        const bf16x8 kf = *(const bf16x8*)(krow + kc * 32 + g * 8);
        S[cn] = __builtin_amdgcn_mfma_f32_16x16x32_bf16(qf[kc], kf, S[cn], 0, 0, 0);
      }
    }
    if (kv0 + 63 > t0) {  // causal mask only on edge tiles
#pragma unroll
      for (int cn = 0; cn < 4; ++cn) {
        const int kv = kv0 + cn * 16 + l15;
#pragma unroll
        for (int r = 0; r < 4; ++r)
          if (kv > t0 + g4 + r) S[cn][r] = -__builtin_inff();
      }
    }
    // wave-parallel online softmax (rows live in 16-lane groups)
    float mloc[4];
#pragma unroll
    for (int r = 0; r < 4; ++r)
      mloc[r] = fmaxf(fmaxf(S[0][r], S[1][r]), fmaxf(S[2][r], S[3][r]));
#pragma unroll
    for (int st = 1; st <= 8; st <<= 1)
#pragma unroll
      for (int r = 0; r < 4; ++r)
        mloc[r] = fmaxf(mloc[r], __shfl_xor(mloc[r], st, 64));
    float sc[4], mnew[4];
#pragma unroll
    for (int r = 0; r < 4; ++r) {
      mnew[r] = fmaxf(m[r], mloc[r]);
      sc[r] = __expf(m[r] - mnew[r]);
      m[r] = mnew[r];
    }
    float psum[4] = {0.f, 0.f, 0.f, 0.f};
#pragma unroll
    for (int cn = 0; cn < 4; ++cn)
#pragma unroll
      for (int r = 0; r < 4; ++r) {
        const float p = __expf(S[cn][r] - mnew[r]);
        S[cn][r] = p;
        psum[r] += p;
      }
#pragma unroll
    for (int st = 1; st <= 8; st <<= 1)
#pragma unroll
      for (int r = 0; r < 4; ++r) psum[r] += __shfl_xor(psum[r], st, 64);
#pragma unroll
    for (int r = 0; r < 4; ++r) lsum[r] = lsum[r] * sc[r] + psum[r];
#pragma unroll
    for (int hc = 0; hc < 8; ++hc)
#pragma unroll
      for (int r = 0; r < 4; ++r) o[hc][r] *= sc[r];
    // P: C-layout -> A-frag layout via swizzled LDS round-trip
    __syncthreads();
#pragma unroll
    for (int cn = 0; cn < 4; ++cn)
#pragma unroll
      for (int r = 0; r < 4; ++r) {
        const int q = g4 + r;
        const int col = cn * 16 + l15;
        P[q * 64 + (col ^ ((q & 7) << 3))] = bf16u(S[cn][r]);
      }
    __syncthreads();
    bf16x8 pf[2];
#pragma unroll
    for (int kvc = 0; kvc < 2; ++kvc)
      pf[kvc] = *(const bf16x8*)(&P[l15 * 64 + (((kvc * 32 + g * 8) ^ ((l15 & 7) << 3)))]);
#pragma unroll
    for (int hc = 0; hc < 8; ++hc) {
      const u16* vrow = vB + (size_t)(hc * 16 + l15) * Tn + kv0;
#pragma unroll
      for (int kvc = 0; kvc < 2; ++kvc) {
        const bf16x8 vf = *(const bf16x8*)(vrow + kvc * 32 + g * 8);
        o[hc] = __builtin_amdgcn_mfma_f32_16x16x32_bf16(pf[kvc], vf, o[hc], 0, 0, 0);
      }
    }
  }
  float inv[4];
#pragma unroll
  for (int r = 0; r < 4; ++r) inv[r] = 1.0f / lsum[r];
#pragma unroll
  for (int hc = 0; hc < 8; ++hc)
#pragma unroll
    for (int r = 0; r < 4; ++r)
      out[(size_t)(b * Tn + t0 + g4 + r) * Hn + hc * 16 + l15] = o[hc][r] * inv[r];
}

extern "C" void kernel_launch(void* const* d_in, const int* in_sizes, int n_in,
                              void* d_out, int out_size, void* d_ws, size_t ws_size,
                              hipStream_t stream) {
  const float* x  = (const float*)d_in[0];
  const float* Wq = (const float*)d_in[1];
  const float* Wk = (const float*)d_in[2];
  const float* Wv = (const float*)d_in[3];
  float* out = (float*)d_out;
  char* ws = (char*)d_ws;
  // ws layout (17 MB total):
  u16* WT = (u16*)(ws);                  // 768 KB: bf16 W^T [3][128][1024]
  u16* qb = (u16*)(ws + (1u << 20));     // 4 MB: q bf16 (pre-scaled)
  u16* kb = (u16*)(ws + (5u << 20));     // 4 MB
  u16* vb = (u16*)(ws + (9u << 20));     // 4 MB
  u16* vt = (u16*)(ws + (13u << 20));    // 4 MB: V^T [b][h][t]

  convert_w_kernel<<<384, 256, 0, stream>>>(Wq, Wk, Wv, WT);
  qkv_gemm_kernel<<<768, 128, 0, stream>>>(x, WT, qb, kb, vb);
  transpose_v_kernel<<<512, 256, 0, stream>>>(vb, vt);
  attention_kernel<<<1024, 64, 0, stream>>>(qb, kb, vt, out);
}

// Round 3
// 216.543 us; speedup vs baseline: 1.2464x; 1.2464x over previous
//
#include <hip/hip_runtime.h>
#include <hip/hip_bf16.h>
#include <stdint.h>

typedef __bf16 bf16x8 __attribute__((ext_vector_type(8)));
typedef float f32x4 __attribute__((ext_vector_type(4)));
typedef unsigned short u16;
typedef u16 u16x8 __attribute__((ext_vector_type(8)));

#define GAS __attribute__((address_space(1)))
#define LAS __attribute__((address_space(3)))

static constexpr int Tn = 2048;
static constexpr int Dn = 1024;
static constexpr int Hn = 128;

__device__ __forceinline__ u16 bf16u(float f) {
  __bf16 h = (__bf16)f;
  return __builtin_bit_cast(u16, h);
}

__device__ __forceinline__ void gl_lds16(const void* g, void* l) {
  __builtin_amdgcn_global_load_lds((GAS void*)g, (LAS void*)l, 16, 0, 0);
}

// ---------------- convert + transpose weights: WT[w][h][d] bf16, Wq pre-scaled ----------------
__global__ __launch_bounds__(256) void convert_w_kernel(
    const float* __restrict__ Wq, const float* __restrict__ Wk,
    const float* __restrict__ Wv, u16* __restrict__ WT) {
  const int bid = blockIdx.x;  // 384 = 3*128
  const int w = bid >> 7;
  const int h = bid & 127;
  const float* src = (w == 0) ? Wq : ((w == 1) ? Wk : Wv);
  const float scale = (w == 0) ? 0.08838834764831845f : 1.0f;  // 1/sqrt(128) folded into Wq
  const int d0 = threadIdx.x * 4;
  ushort4 v;
  v.x = bf16u(src[(size_t)(d0 + 0) * Hn + h] * scale);
  v.y = bf16u(src[(size_t)(d0 + 1) * Hn + h] * scale);
  v.z = bf16u(src[(size_t)(d0 + 2) * Hn + h] * scale);
  v.w = bf16u(src[(size_t)(d0 + 3) * Hn + h] * scale);
  *(ushort4*)(&WT[(size_t)(w * Hn + h) * Dn + d0]) = v;
}

// ---------------- QKV projection GEMM: [16384x1024] x [1024x128] per weight ----------------
// grid 768 = 256 m-tiles(64 rows) * 3 weights; block 128 thr = 2 waves; wave tile 64x64
__global__ __launch_bounds__(128) void qkv_gemm_kernel(
    const float* __restrict__ x, const u16* __restrict__ WT,
    u16* __restrict__ qb, u16* __restrict__ kb, u16* __restrict__ vb) {
  __shared__ u16 As[64 * 64];   // [row][64 k] bf16, XOR-swizzled 16B units
  __shared__ u16 Bs[128 * 64];  // [n][64 k] bf16, XOR-swizzled (pre-swizzled global src)
  const int bid = blockIdx.x;
  const int w = bid % 3;            // 3 sibling blocks share an x-tile (L2/L3 reuse)
  const int m0 = (bid / 3) * 64;
  const int tid = threadIdx.x;
  const int lane = tid & 63;
  const int wid = tid >> 6;
  const int l15 = lane & 15;
  const int g = lane >> 4;

  const u16* wt = WT + (size_t)w * (Hn * Dn);

  const f32x4 fz = {0.f, 0.f, 0.f, 0.f};
  f32x4 acc[4][4];
#pragma unroll
  for (int i = 0; i < 4; ++i)
#pragma unroll
    for (int j = 0; j < 4; ++j) acc[i][j] = fz;

  for (int k0 = 0; k0 < Dn; k0 += 64) {
    // stage A: fp32 -> bf16 convert, XOR-swizzled LDS write
#pragma unroll
    for (int j = 0; j < 8; ++j) {
      const int s = j * 128 + tid;
      const int row = s >> 4;
      const int c16 = s & 15;  // 4-float unit within row
      const float4 fa = *(const float4*)(x + (size_t)(m0 + row) * Dn + k0 + c16 * 4);
      const int u = c16 >> 1, half = c16 & 1;
      const int slot = u ^ (row & 7);
      ushort4 pk;
      pk.x = bf16u(fa.x); pk.y = bf16u(fa.y); pk.z = bf16u(fa.z); pk.w = bf16u(fa.w);
      *(ushort4*)(&As[row * 64 + slot * 8 + half * 4]) = pk;
    }
    // stage B: global_load_lds (linear LDS dest, pre-swizzled global source)
#pragma unroll
    for (int i = 0; i < 8; ++i) {
      const int s = i * 128 + tid;
      const int n = s >> 3;
      const int us = s & 7;
      const u16* gsrc = wt + (size_t)n * Dn + k0 + ((us ^ (n & 7)) * 8);
      gl_lds16(gsrc, &Bs[(i * 128 + wid * 64) * 8]);
    }
    __syncthreads();
#pragma unroll
    for (int kc = 0; kc < 2; ++kc) {
      bf16x8 af[4], bfr[4];
#pragma unroll
      for (int mi = 0; mi < 4; ++mi) {
        const int row = mi * 16 + l15;
        af[mi] = *(const bf16x8*)(&As[row * 64 + (((kc * 4 + g) ^ (row & 7)) * 8)]);
      }
#pragma unroll
      for (int ni = 0; ni < 4; ++ni) {
        const int n = wid * 64 + ni * 16 + l15;
        bfr[ni] = *(const bf16x8*)(&Bs[n * 64 + (((kc * 4 + g) ^ (n & 7)) * 8)]);
      }
#pragma unroll
      for (int mi = 0; mi < 4; ++mi)
#pragma unroll
        for (int ni = 0; ni < 4; ++ni)
          acc[mi][ni] = __builtin_amdgcn_mfma_f32_16x16x32_bf16(af[mi], bfr[ni], acc[mi][ni], 0, 0, 0);
    }
    __syncthreads();
  }
  u16* dst = (w == 0) ? qb : ((w == 1) ? kb : vb);
#pragma unroll
  for (int mi = 0; mi < 4; ++mi)
#pragma unroll
    for (int ni = 0; ni < 4; ++ni)
#pragma unroll
      for (int r = 0; r < 4; ++r)
        dst[(size_t)(m0 + mi * 16 + g * 4 + r) * Hn + wid * 64 + ni * 16 + l15] =
            bf16u(acc[mi][ni][r]);
}

// ---------------- V transpose: vb[b][t][h] -> vt[b][h][t] ----------------
__global__ __launch_bounds__(256) void transpose_v_kernel(
    const u16* __restrict__ vb, u16* __restrict__ vt) {
  __shared__ u16 tile[64 * 64];
  const int bid = blockIdx.x;  // 512 = 8b * 32tt * 2hh
  const int b = bid >> 6;
  const int rem = bid & 63;
  const int t0 = (rem >> 1) * 64, h0 = (rem & 1) * 64;
  const int tid = threadIdx.x;
  {
    const int r = tid >> 2, cq = tid & 3;
    const u16* src = vb + (size_t)(b * Tn + t0 + r) * Hn + h0 + cq * 16;
#pragma unroll
    for (int s = 0; s < 2; ++s) {
      u16x8 v = *(const u16x8*)(src + s * 8);
      const int u = cq * 2 + s;
      *(u16x8*)(&tile[r * 64 + (u ^ (r & 7)) * 8]) = v;
    }
  }
  __syncthreads();
  {
    const int hr = tid >> 2, tg = tid & 3;
    u16 outv[16];
#pragma unroll
    for (int j = 0; j < 16; ++j) {
      const int tl = tg * 16 + j;
      outv[j] = tile[tl * 64 + (((hr >> 3) ^ (tl & 7)) * 8) + (hr & 7)];
    }
    u16* dstp = vt + (size_t)(b * Hn + h0 + hr) * Tn + t0 + tg * 16;
    *(u16x8*)(dstp) = *(const u16x8*)(&outv[0]);
    *(u16x8*)(dstp + 8) = *(const u16x8*)(&outv[8]);
  }
}

// ---------------- flash attention: 4 waves/block, KV tiles striped across waves ----------------
// block = (b, 16-row q-tile); wave w handles kv tiles w, w+4, ...; flash combine in LDS.
__global__ __launch_bounds__(256) void attention_kernel(
    const u16* __restrict__ qb, const u16* __restrict__ kb,
    const u16* __restrict__ vt, float* __restrict__ out) {
  __shared__ u16 Pb[4][16 * 64];     // per-wave P round-trip, XOR-swizzled
  __shared__ float oA[16][132];      // combined output accum (pad 132: 2-way banks)
  __shared__ float mS[4][16];
  __shared__ float lS[4][16];
  const int bid = blockIdx.x;  // 1024 = 8 batches (bid&7 -> XCD) * 128 q-tiles
  const int b = bid & 7;
  const int t0 = (bid >> 3) * 16;
  const int tid = threadIdx.x;
  const int wid = tid >> 6;
  const int lane = tid & 63;
  const int l15 = lane & 15;
  const int g = lane >> 4;
  const int g4 = g * 4;

  const u16* qB = qb + (size_t)b * Tn * Hn;
  const u16* kB = kb + (size_t)b * Tn * Hn;
  const u16* vB = vt + (size_t)b * Hn * Tn;

  bf16x8 qf[4];
#pragma unroll
  for (int kc = 0; kc < 4; ++kc)
    qf[kc] = *(const bf16x8*)(qB + (size_t)(t0 + l15) * Hn + kc * 32 + g * 8);

  const f32x4 fz = {0.f, 0.f, 0.f, 0.f};
  f32x4 o[8];
#pragma unroll
  for (int hc = 0; hc < 8; ++hc) o[hc] = fz;
  float m[4], lsum[4];
#pragma unroll
  for (int r = 0; r < 4; ++r) { m[r] = -__builtin_inff(); lsum[r] = 0.f; }

  u16* P = &Pb[wid][0];
  const int nt = ((t0 + 15) >> 6) + 1;  // kv tiles in causal range

  for (int t = wid; t < nt; t += 4) {
    const int kv0 = t * 64;
    f32x4 S[4];
#pragma unroll
    for (int cn = 0; cn < 4; ++cn) S[cn] = fz;
#pragma unroll
    for (int cn = 0; cn < 4; ++cn) {
      const u16* krow = kB + (size_t)(kv0 + cn * 16 + l15) * Hn;
#pragma unroll
      for (int kc = 0; kc < 4; ++kc) {
        const bf16x8 kf = *(const bf16x8*)(krow + kc * 32 + g * 8);
        S[cn] = __builtin_amdgcn_mfma_f32_16x16x32_bf16(qf[kc], kf, S[cn], 0, 0, 0);
      }
    }
    if (kv0 + 63 > t0) {  // causal mask only on edge tiles
#pragma unroll
      for (int cn = 0; cn < 4; ++cn) {
        const int kv = kv0 + cn * 16 + l15;
#pragma unroll
        for (int r = 0; r < 4; ++r)
          if (kv > t0 + g4 + r) S[cn][r] = -__builtin_inff();
      }
    }
    // wave-parallel online softmax (rows live in 16-lane groups)
    float mloc[4];
#pragma unroll
    for (int r = 0; r < 4; ++r)
      mloc[r] = fmaxf(fmaxf(S[0][r], S[1][r]), fmaxf(S[2][r], S[3][r]));
#pragma unroll
    for (int st = 1; st <= 8; st <<= 1)
#pragma unroll
      for (int r = 0; r < 4; ++r)
        mloc[r] = fmaxf(mloc[r], __shfl_xor(mloc[r], st, 64));
    float sc[4], mnew[4];
#pragma unroll
    for (int r = 0; r < 4; ++r) {
      mnew[r] = fmaxf(m[r], mloc[r]);
      sc[r] = __expf(m[r] - mnew[r]);
      m[r] = mnew[r];
    }
    float psum[4] = {0.f, 0.f, 0.f, 0.f};
#pragma unroll
    for (int cn = 0; cn < 4; ++cn)
#pragma unroll
      for (int r = 0; r < 4; ++r) {
        const float p = __expf(S[cn][r] - mnew[r]);
        S[cn][r] = p;
        psum[r] += p;
      }
#pragma unroll
    for (int st = 1; st <= 8; st <<= 1)
#pragma unroll
      for (int r = 0; r < 4; ++r) psum[r] += __shfl_xor(psum[r], st, 64);
#pragma unroll
    for (int r = 0; r < 4; ++r) lsum[r] = lsum[r] * sc[r] + psum[r];
#pragma unroll
    for (int hc = 0; hc < 8; ++hc)
#pragma unroll
      for (int r = 0; r < 4; ++r) o[hc][r] *= sc[r];
    // P: C-layout -> A-frag layout via per-wave swizzled LDS round-trip.
    // Wave-local ordering only: same-wave LDS ops are in-order; lgkmcnt(0)
    // makes all lanes' writes visible before the cross-lane reads.
    asm volatile("s_waitcnt lgkmcnt(0)" ::: "memory");  // prior reads done before overwrite
#pragma unroll
    for (int cn = 0; cn < 4; ++cn)
#pragma unroll
      for (int r = 0; r < 4; ++r) {
        const int q = g4 + r;
        const int col = cn * 16 + l15;
        P[q * 64 + (col ^ ((q & 7) << 3))] = bf16u(S[cn][r]);
      }
    asm volatile("s_waitcnt lgkmcnt(0)" ::: "memory");
    bf16x8 pf[2];
#pragma unroll
    for (int kvc = 0; kvc < 2; ++kvc)
      pf[kvc] = *(const bf16x8*)(&P[l15 * 64 + (((kvc * 32 + g * 8) ^ ((l15 & 7) << 3)))]);
#pragma unroll
    for (int hc = 0; hc < 8; ++hc) {
      const u16* vrow = vB + (size_t)(hc * 16 + l15) * Tn + kv0;
#pragma unroll
      for (int kvc = 0; kvc < 2; ++kvc) {
        const bf16x8 vf = *(const bf16x8*)(vrow + kvc * 32 + g * 8);
        o[hc] = __builtin_amdgcn_mfma_f32_16x16x32_bf16(pf[kvc], vf, o[hc], 0, 0, 0);
      }
    }
  }

  // ---- flash combine across the 4 waves ----
  if (l15 == 0) {
#pragma unroll
    for (int r = 0; r < 4; ++r) { mS[wid][g4 + r] = m[r]; lS[wid][g4 + r] = lsum[r]; }
  }
  __syncthreads();
  float fac[4];
#pragma unroll
  for (int r = 0; r < 4; ++r) {
    const int row = g4 + r;
    const float M = fmaxf(fmaxf(mS[0][row], mS[1][row]), fmaxf(mS[2][row], mS[3][row]));
    fac[r] = __expf(m[r] - M);  // 0 for waves with no tiles (m = -inf)
  }
#pragma unroll
  for (int hc = 0; hc < 8; ++hc)
#pragma unroll
    for (int r = 0; r < 4; ++r) o[hc][r] *= fac[r];
  for (int w2 = 0; w2 < 4; ++w2) {
    if (wid == w2) {
#pragma unroll
      for (int hc = 0; hc < 8; ++hc)
#pragma unroll
        for (int r = 0; r < 4; ++r) {
          if (w2 == 0) oA[g4 + r][hc * 16 + l15] = o[hc][r];
          else oA[g4 + r][hc * 16 + l15] += o[hc][r];
        }
    }
    __syncthreads();
  }
  {
    const int row = tid >> 4;
    const int c0 = tid & 15;
    const float M = fmaxf(fmaxf(mS[0][row], mS[1][row]), fmaxf(mS[2][row], mS[3][row]));
    float L = 0.f;
#pragma unroll
    for (int w2 = 0; w2 < 4; ++w2) L += __expf(mS[w2][row] - M) * lS[w2][row];
    const float invL = 1.0f / L;
    float* orow = out + (size_t)(b * Tn + t0 + row) * Hn;
#pragma unroll
    for (int j = 0; j < 8; ++j) orow[c0 + 16 * j] = oA[row][c0 + 16 * j] * invL;
  }
}

extern "C" void kernel_launch(void* const* d_in, const int* in_sizes, int n_in,
                              void* d_out, int out_size, void* d_ws, size_t ws_size,
                              hipStream_t stream) {
  const float* x  = (const float*)d_in[0];
  const float* Wq = (const float*)d_in[1];
  const float* Wk = (const float*)d_in[2];
  const float* Wv = (const float*)d_in[3];
  float* out = (float*)d_out;
  char* ws = (char*)d_ws;
  // ws layout (17 MB total):
  u16* WT = (u16*)(ws);                  // 768 KB: bf16 W^T [3][128][1024]
  u16* qb = (u16*)(ws + (1u << 20));     // 4 MB: q bf16 (pre-scaled)
  u16* kb = (u16*)(ws + (5u << 20));     // 4 MB
  u16* vb = (u16*)(ws + (9u << 20));     // 4 MB
  u16* vt = (u16*)(ws + (13u << 20));    // 4 MB: V^T [b][h][t]

  convert_w_kernel<<<384, 256, 0, stream>>>(Wq, Wk, Wv, WT);
  qkv_gemm_kernel<<<768, 128, 0, stream>>>(x, WT, qb, kb, vb);
  transpose_v_kernel<<<512, 256, 0, stream>>>(vb, vt);
  attention_kernel<<<1024, 256, 0, stream>>>(qb, kb, vt, out);
}

// Round 4
// 207.834 us; speedup vs baseline: 1.2986x; 1.0419x over previous
//
#include <hip/hip_runtime.h>
#include <hip/hip_bf16.h>
#include <stdint.h>

typedef __bf16 bf16x8 __attribute__((ext_vector_type(8)));
typedef float f32x4 __attribute__((ext_vector_type(4)));
typedef unsigned short u16;
typedef u16 u16x8 __attribute__((ext_vector_type(8)));

#define GAS __attribute__((address_space(1)))
#define LAS __attribute__((address_space(3)))

static constexpr int Tn = 2048;
static constexpr int Dn = 1024;
static constexpr int Hn = 128;

__device__ __forceinline__ u16 bf16u(float f) {
  __bf16 h = (__bf16)f;
  return __builtin_bit_cast(u16, h);
}

__device__ __forceinline__ void gl_lds16(const void* g, void* l) {
  __builtin_amdgcn_global_load_lds((GAS void*)g, (LAS void*)l, 16, 0, 0);
}

// ---------------- convert + transpose weights: WT[w][h][d] bf16, Wq pre-scaled ----------------
__global__ __launch_bounds__(256) void convert_w_kernel(
    const float* __restrict__ Wq, const float* __restrict__ Wk,
    const float* __restrict__ Wv, u16* __restrict__ WT) {
  const int bid = blockIdx.x;  // 384 = 3*128
  const int w = bid >> 7;
  const int h = bid & 127;
  const float* src = (w == 0) ? Wq : ((w == 1) ? Wk : Wv);
  const float scale = (w == 0) ? 0.08838834764831845f : 1.0f;  // 1/sqrt(128) folded into Wq
  const int d0 = threadIdx.x * 4;
  ushort4 v;
  v.x = bf16u(src[(size_t)(d0 + 0) * Hn + h] * scale);
  v.y = bf16u(src[(size_t)(d0 + 1) * Hn + h] * scale);
  v.z = bf16u(src[(size_t)(d0 + 2) * Hn + h] * scale);
  v.w = bf16u(src[(size_t)(d0 + 3) * Hn + h] * scale);
  *(ushort4*)(&WT[(size_t)(w * Hn + h) * Dn + d0]) = v;
}

// ---------------- fused QKV GEMM: [16384x1024] x [1024x384] (q|k|v), x read ONCE ----------------
// grid 512 m-tiles (32 rows); block 512 thr = 8 waves; wave tile 32x48 (acc[2][3])
__global__ __launch_bounds__(512, 4) void qkv_gemm_kernel(
    const float* __restrict__ x, const u16* __restrict__ WT,
    u16* __restrict__ qb, u16* __restrict__ kb, u16* __restrict__ vb) {
  __shared__ u16 As[32 * 64];   // [row][64 k] bf16, XOR-swizzled 16B units (4 KB)
  __shared__ u16 Bs[384 * 64];  // [n][64 k] bf16, XOR-swizzled via pre-swizzled src (48 KB)
  const int m0 = blockIdx.x * 32;
  const int tid = threadIdx.x;
  const int lane = tid & 63;
  const int wid = tid >> 6;
  const int l15 = lane & 15;
  const int g = lane >> 4;
  const int g4 = g * 4;

  const f32x4 fz = {0.f, 0.f, 0.f, 0.f};
  f32x4 acc[2][3];
#pragma unroll
  for (int i = 0; i < 2; ++i)
#pragma unroll
    for (int j = 0; j < 3; ++j) acc[i][j] = fz;

  // A-stage indices: 32 rows x 16 float4-units = 512 threads exactly
  const int arow = tid >> 4;
  const int c16 = tid & 15;
  const int aslot = (c16 >> 1) ^ (arow & 7);
  const int ahalf = c16 & 1;

  for (int k0 = 0; k0 < Dn; k0 += 64) {
    // stage A: fp32 -> bf16 convert, XOR-swizzled LDS write
    {
      const float4 fa = *(const float4*)(x + (size_t)(m0 + arow) * Dn + k0 + c16 * 4);
      ushort4 pk;
      pk.x = bf16u(fa.x); pk.y = bf16u(fa.y); pk.z = bf16u(fa.z); pk.w = bf16u(fa.w);
      *(ushort4*)(&As[arow * 64 + aslot * 8 + ahalf * 4]) = pk;
    }
    // stage B: 384 rows x 8 units = 3072 units = 6 x 512 threads
#pragma unroll
    for (int i = 0; i < 6; ++i) {
      const int s = i * 512 + tid;
      const int n = s >> 3;
      const int us = s & 7;
      const u16* gsrc = WT + (size_t)n * Dn + k0 + ((us ^ (n & 7)) * 8);
      gl_lds16(gsrc, &Bs[(i * 512 + wid * 64) * 8]);
    }
    __syncthreads();
#pragma unroll
    for (int kc = 0; kc < 2; ++kc) {
      bf16x8 af[2], bfr[3];
#pragma unroll
      for (int mi = 0; mi < 2; ++mi) {
        const int row = mi * 16 + l15;
        af[mi] = *(const bf16x8*)(&As[row * 64 + (((kc * 4 + g) ^ (row & 7)) * 8)]);
      }
#pragma unroll
      for (int ni = 0; ni < 3; ++ni) {
        const int n = wid * 48 + ni * 16 + l15;
        bfr[ni] = *(const bf16x8*)(&Bs[n * 64 + (((kc * 4 + g) ^ (n & 7)) * 8)]);
      }
#pragma unroll
      for (int mi = 0; mi < 2; ++mi)
#pragma unroll
        for (int ni = 0; ni < 3; ++ni)
          acc[mi][ni] = __builtin_amdgcn_mfma_f32_16x16x32_bf16(af[mi], bfr[ni], acc[mi][ni], 0, 0, 0);
    }
    __syncthreads();
  }
  // C-write: n = wid*48 + ni*16 + l15; each (wid,ni) span lies in exactly one of q/k/v
#pragma unroll
  for (int mi = 0; mi < 2; ++mi)
#pragma unroll
    for (int ni = 0; ni < 3; ++ni) {
      const int nb = wid * 48 + ni * 16;
      const int w = nb >> 7;
      u16* dst = (w == 0) ? qb : ((w == 1) ? kb : vb);
      const int h = (nb & 127) + l15;
#pragma unroll
      for (int r = 0; r < 4; ++r)
        dst[(size_t)(m0 + mi * 16 + g4 + r) * Hn + h] = bf16u(acc[mi][ni][r]);
    }
}

// ---------------- V transpose: vb[b][t][h] -> vt[b][h][t] ----------------
__global__ __launch_bounds__(256) void transpose_v_kernel(
    const u16* __restrict__ vb, u16* __restrict__ vt) {
  __shared__ u16 tile[64 * 64];
  const int bid = blockIdx.x;  // 512 = 8b * 32tt * 2hh
  const int b = bid >> 6;
  const int rem = bid & 63;
  const int t0 = (rem >> 1) * 64, h0 = (rem & 1) * 64;
  const int tid = threadIdx.x;
  {
    const int r = tid >> 2, cq = tid & 3;
    const u16* src = vb + (size_t)(b * Tn + t0 + r) * Hn + h0 + cq * 16;
#pragma unroll
    for (int s = 0; s < 2; ++s) {
      u16x8 v = *(const u16x8*)(src + s * 8);
      const int u = cq * 2 + s;
      *(u16x8*)(&tile[r * 64 + (u ^ (r & 7)) * 8]) = v;
    }
  }
  __syncthreads();
  {
    const int hr = tid >> 2, tg = tid & 3;
    u16 outv[16];
#pragma unroll
    for (int j = 0; j < 16; ++j) {
      const int tl = tg * 16 + j;
      outv[j] = tile[tl * 64 + (((hr >> 3) ^ (tl & 7)) * 8) + (hr & 7)];
    }
    u16* dstp = vt + (size_t)(b * Hn + h0 + hr) * Tn + t0 + tg * 16;
    *(u16x8*)(dstp) = *(const u16x8*)(&outv[0]);
    *(u16x8*)(dstp + 8) = *(const u16x8*)(&outv[8]);
  }
}

// ---------------- flash attention: 8 waves/block, KV tiles striped, tree combine ----------------
__global__ __launch_bounds__(512, 4) void attention_kernel(
    const u16* __restrict__ qb, const u16* __restrict__ kb,
    const u16* __restrict__ vt, float* __restrict__ out) {
  __shared__ u16 Pb[8][16 * 64];     // per-wave P round-trip, XOR-swizzled (16 KB)
  __shared__ float oB[4][16][132];   // tree-reduce buffer, padded (33 KB)
  __shared__ float mS[8][16];
  __shared__ float lS[8][16];
  const int bid = blockIdx.x;  // 1024 = 8 batches (bid&7 -> XCD) * 128 q-tiles
  const int b = bid & 7;
  const int t0 = (bid >> 3) * 16;
  const int tid = threadIdx.x;
  const int wid = tid >> 6;
  const int lane = tid & 63;
  const int l15 = lane & 15;
  const int g = lane >> 4;
  const int g4 = g * 4;

  const u16* qB = qb + (size_t)b * Tn * Hn;
  const u16* kB = kb + (size_t)b * Tn * Hn;
  const u16* vB = vt + (size_t)b * Hn * Tn;

  bf16x8 qf[4];
#pragma unroll
  for (int kc = 0; kc < 4; ++kc)
    qf[kc] = *(const bf16x8*)(qB + (size_t)(t0 + l15) * Hn + kc * 32 + g * 8);

  const f32x4 fz = {0.f, 0.f, 0.f, 0.f};
  f32x4 o[8];
#pragma unroll
  for (int hc = 0; hc < 8; ++hc) o[hc] = fz;
  float m[4], lsum[4];
#pragma unroll
  for (int r = 0; r < 4; ++r) { m[r] = -__builtin_inff(); lsum[r] = 0.f; }

  u16* P = &Pb[wid][0];
  const int nt = ((t0 + 15) >> 6) + 1;  // kv tiles in causal range

  for (int t = wid; t < nt; t += 8) {
    const int kv0 = t * 64;
    f32x4 S[4];
#pragma unroll
    for (int cn = 0; cn < 4; ++cn) S[cn] = fz;
#pragma unroll
    for (int cn = 0; cn < 4; ++cn) {
      const u16* krow = kB + (size_t)(kv0 + cn * 16 + l15) * Hn;
#pragma unroll
      for (int kc = 0; kc < 4; ++kc) {
        const bf16x8 kf = *(const bf16x8*)(krow + kc * 32 + g * 8);
        S[cn] = __builtin_amdgcn_mfma_f32_16x16x32_bf16(qf[kc], kf, S[cn], 0, 0, 0);
      }
    }
    if (kv0 + 63 > t0) {  // causal mask only on edge tiles
#pragma unroll
      for (int cn = 0; cn < 4; ++cn) {
        const int kv = kv0 + cn * 16 + l15;
#pragma unroll
        for (int r = 0; r < 4; ++r)
          if (kv > t0 + g4 + r) S[cn][r] = -__builtin_inff();
      }
    }
    // wave-parallel online softmax (rows live in 16-lane groups)
    float mloc[4];
#pragma unroll
    for (int r = 0; r < 4; ++r)
      mloc[r] = fmaxf(fmaxf(S[0][r], S[1][r]), fmaxf(S[2][r], S[3][r]));
#pragma unroll
    for (int st = 1; st <= 8; st <<= 1)
#pragma unroll
      for (int r = 0; r < 4; ++r)
        mloc[r] = fmaxf(mloc[r], __shfl_xor(mloc[r], st, 64));
    float sc[4], mnew[4];
#pragma unroll
    for (int r = 0; r < 4; ++r) {
      mnew[r] = fmaxf(m[r], mloc[r]);
      sc[r] = __expf(m[r] - mnew[r]);
      m[r] = mnew[r];
    }
    float psum[4] = {0.f, 0.f, 0.f, 0.f};
#pragma unroll
    for (int cn = 0; cn < 4; ++cn)
#pragma unroll
      for (int r = 0; r < 4; ++r) {
        const float p = __expf(S[cn][r] - mnew[r]);
        S[cn][r] = p;
        psum[r] += p;
      }
#pragma unroll
    for (int st = 1; st <= 8; st <<= 1)
#pragma unroll
      for (int r = 0; r < 4; ++r) psum[r] += __shfl_xor(psum[r], st, 64);
#pragma unroll
    for (int r = 0; r < 4; ++r) lsum[r] = lsum[r] * sc[r] + psum[r];
#pragma unroll
    for (int hc = 0; hc < 8; ++hc)
#pragma unroll
      for (int r = 0; r < 4; ++r) o[hc][r] *= sc[r];
    // P: C-layout -> A-frag layout via per-wave swizzled LDS round-trip.
    // Wave-local ordering only: same-wave LDS ops are in-order; lgkmcnt(0)
    // makes all lanes' writes visible before the cross-lane reads.
    asm volatile("s_waitcnt lgkmcnt(0)" ::: "memory");  // prior reads done before overwrite
#pragma unroll
    for (int cn = 0; cn < 4; ++cn)
#pragma unroll
      for (int r = 0; r < 4; ++r) {
        const int q = g4 + r;
        const int col = cn * 16 + l15;
        P[q * 64 + (col ^ ((q & 7) << 3))] = bf16u(S[cn][r]);
      }
    asm volatile("s_waitcnt lgkmcnt(0)" ::: "memory");
    bf16x8 pf[2];
#pragma unroll
    for (int kvc = 0; kvc < 2; ++kvc)
      pf[kvc] = *(const bf16x8*)(&P[l15 * 64 + (((kvc * 32 + g * 8) ^ ((l15 & 7) << 3)))]);
#pragma unroll
    for (int hc = 0; hc < 8; ++hc) {
      const u16* vrow = vB + (size_t)(hc * 16 + l15) * Tn + kv0;
#pragma unroll
      for (int kvc = 0; kvc < 2; ++kvc) {
        const bf16x8 vf = *(const bf16x8*)(vrow + kvc * 32 + g * 8);
        o[hc] = __builtin_amdgcn_mfma_f32_16x16x32_bf16(pf[kvc], vf, o[hc], 0, 0, 0);
      }
    }
  }

  // ---- flash combine across 8 waves (log tree) ----
  if (l15 == 0) {
#pragma unroll
    for (int r = 0; r < 4; ++r) { mS[wid][g4 + r] = m[r]; lS[wid][g4 + r] = lsum[r]; }
  }
  __syncthreads();
  float M[4];
#pragma unroll
  for (int r = 0; r < 4; ++r) {
    const int row = g4 + r;
    float mm = mS[0][row];
#pragma unroll
    for (int w2 = 1; w2 < 8; ++w2) mm = fmaxf(mm, mS[w2][row]);
    M[r] = mm;
    const float fac = __expf(m[r] - mm);  // 0 for waves with no tiles
#pragma unroll
    for (int hc = 0; hc < 8; ++hc) o[hc][r] *= fac;
  }
  // tree: 8 -> 4 -> 2 -> 1
  if (wid >= 4) {
#pragma unroll
    for (int hc = 0; hc < 8; ++hc)
#pragma unroll
      for (int r = 0; r < 4; ++r) oB[wid - 4][g4 + r][hc * 16 + l15] = o[hc][r];
  }
  __syncthreads();
  if (wid < 4) {
#pragma unroll
    for (int hc = 0; hc < 8; ++hc)
#pragma unroll
      for (int r = 0; r < 4; ++r) o[hc][r] += oB[wid][g4 + r][hc * 16 + l15];
  }
  __syncthreads();
  if (wid == 2 || wid == 3) {
#pragma unroll
    for (int hc = 0; hc < 8; ++hc)
#pragma unroll
      for (int r = 0; r < 4; ++r) oB[wid - 2][g4 + r][hc * 16 + l15] = o[hc][r];
  }
  __syncthreads();
  if (wid < 2) {
#pragma unroll
    for (int hc = 0; hc < 8; ++hc)
#pragma unroll
      for (int r = 0; r < 4; ++r) o[hc][r] += oB[wid][g4 + r][hc * 16 + l15];
  }
  __syncthreads();
  if (wid == 1) {
#pragma unroll
    for (int hc = 0; hc < 8; ++hc)
#pragma unroll
      for (int r = 0; r < 4; ++r) oB[0][g4 + r][hc * 16 + l15] = o[hc][r];
  }
  __syncthreads();
  if (wid == 0) {
    float invL[4];
#pragma unroll
    for (int r = 0; r < 4; ++r) {
      const int row = g4 + r;
      float L = 0.f;
#pragma unroll
      for (int w2 = 0; w2 < 8; ++w2) L += __expf(mS[w2][row] - M[r]) * lS[w2][row];
      invL[r] = 1.0f / L;
    }
#pragma unroll
    for (int hc = 0; hc < 8; ++hc)
#pragma unroll
      for (int r = 0; r < 4; ++r) {
        const float v = (o[hc][r] + oB[0][g4 + r][hc * 16 + l15]) * invL[r];
        out[(size_t)(b * Tn + t0 + g4 + r) * Hn + hc * 16 + l15] = v;
      }
  }
}

extern "C" void kernel_launch(void* const* d_in, const int* in_sizes, int n_in,
                              void* d_out, int out_size, void* d_ws, size_t ws_size,
                              hipStream_t stream) {
  const float* x  = (const float*)d_in[0];
  const float* Wq = (const float*)d_in[1];
  const float* Wk = (const float*)d_in[2];
  const float* Wv = (const float*)d_in[3];
  float* out = (float*)d_out;
  char* ws = (char*)d_ws;
  // ws layout (17 MB total):
  u16* WT = (u16*)(ws);                  // 768 KB: bf16 W^T [3][128][1024] == [384][1024]
  u16* qb = (u16*)(ws + (1u << 20));     // 4 MB: q bf16 (pre-scaled)
  u16* kb = (u16*)(ws + (5u << 20));     // 4 MB
  u16* vb = (u16*)(ws + (9u << 20));     // 4 MB
  u16* vt = (u16*)(ws + (13u << 20));    // 4 MB: V^T [b][h][t]

  convert_w_kernel<<<384, 256, 0, stream>>>(Wq, Wk, Wv, WT);
  qkv_gemm_kernel<<<512, 512, 0, stream>>>(x, WT, qb, kb, vb);
  transpose_v_kernel<<<512, 256, 0, stream>>>(vb, vt);
  attention_kernel<<<1024, 512, 0, stream>>>(qb, kb, vt, out);
}

// Round 5
// 165.408 us; speedup vs baseline: 1.6317x; 1.2565x over previous
//
#include <hip/hip_runtime.h>
#include <hip/hip_bf16.h>
#include <stdint.h>

typedef __bf16 bf16x8 __attribute__((ext_vector_type(8)));
typedef float f32x4 __attribute__((ext_vector_type(4)));
typedef unsigned short u16;
typedef u16 u16x8 __attribute__((ext_vector_type(8)));

#define GAS __attribute__((address_space(1)))
#define LAS __attribute__((address_space(3)))

static constexpr int Tn = 2048;
static constexpr int Dn = 1024;
static constexpr int Hn = 128;

__device__ __forceinline__ u16 bf16u(float f) {
  __bf16 h = (__bf16)f;
  return __builtin_bit_cast(u16, h);
}
__device__ __forceinline__ float u16f(u16 u) {
  uint32_t t = (uint32_t)u << 16;
  return __builtin_bit_cast(float, t);
}

__device__ __forceinline__ void gl_lds16(const void* g, void* l) {
  __builtin_amdgcn_global_load_lds((GAS void*)g, (LAS void*)l, 16, 0, 0);
}

// ---------------- convert + transpose weights: WT[w][h][d] bf16, Wq pre-scaled ----------------
__global__ __launch_bounds__(256) void convert_w_kernel(
    const float* __restrict__ Wq, const float* __restrict__ Wk,
    const float* __restrict__ Wv, u16* __restrict__ WT) {
  const int bid = blockIdx.x;  // 384 = 3*128
  const int w = bid >> 7;
  const int h = bid & 127;
  const float* src = (w == 0) ? Wq : ((w == 1) ? Wk : Wv);
  const float scale = (w == 0) ? 0.08838834764831845f : 1.0f;  // 1/sqrt(128) folded into Wq
  const int d0 = threadIdx.x * 4;
  ushort4 v;
  v.x = bf16u(src[(size_t)(d0 + 0) * Hn + h] * scale);
  v.y = bf16u(src[(size_t)(d0 + 1) * Hn + h] * scale);
  v.z = bf16u(src[(size_t)(d0 + 2) * Hn + h] * scale);
  v.w = bf16u(src[(size_t)(d0 + 3) * Hn + h] * scale);
  *(ushort4*)(&WT[(size_t)(w * Hn + h) * Dn + d0]) = v;
}

// ---------------- fused QKV GEMM: [16384x1024] x [1024x384] (q|k|v), x read ONCE ----------------
// grid 512 m-tiles (32 rows); block 512 thr = 8 waves; wave tile 32x48 (acc[2][3])
// A-tile prefetched into registers during MFMA phase; barrier2 is RAW (no vmcnt drain).
__global__ __launch_bounds__(512, 4) void qkv_gemm_kernel(
    const float* __restrict__ x, const u16* __restrict__ WT,
    u16* __restrict__ qb, u16* __restrict__ kb, u16* __restrict__ vb) {
  __shared__ u16 As[32 * 64];   // [row][64 k] bf16, XOR-swizzled 16B units (4 KB)
  __shared__ u16 Bs[384 * 64];  // [n][64 k] bf16, XOR-swizzled via pre-swizzled src (48 KB)
  const int m0 = blockIdx.x * 32;
  const int tid = threadIdx.x;
  const int lane = tid & 63;
  const int wid = tid >> 6;
  const int l15 = lane & 15;
  const int g = lane >> 4;
  const int g4 = g * 4;

  const f32x4 fz = {0.f, 0.f, 0.f, 0.f};
  f32x4 acc[2][3];
#pragma unroll
  for (int i = 0; i < 2; ++i)
#pragma unroll
    for (int j = 0; j < 3; ++j) acc[i][j] = fz;

  // A-stage indices: 32 rows x 16 float4-units = 512 threads exactly
  const int arow = tid >> 4;
  const int c16 = tid & 15;
  const int aslot = (c16 >> 1) ^ (arow & 7);
  const int ahalf = c16 & 1;
  const float* aptr = x + (size_t)(m0 + arow) * Dn + c16 * 4;

  float4 fa = *(const float4*)(aptr);  // prefetch k0=0

  for (int k0 = 0; k0 < Dn; k0 += 64) {
    // stage A: fp32 -> bf16 convert, XOR-swizzled LDS write
    {
      ushort4 pk;
      pk.x = bf16u(fa.x); pk.y = bf16u(fa.y); pk.z = bf16u(fa.z); pk.w = bf16u(fa.w);
      *(ushort4*)(&As[arow * 64 + aslot * 8 + ahalf * 4]) = pk;
    }
    // stage B: 384 rows x 8 units = 3072 units = 6 x 512 threads
#pragma unroll
    for (int i = 0; i < 6; ++i) {
      const int s = i * 512 + tid;
      const int n = s >> 3;
      const int us = s & 7;
      const u16* gsrc = WT + (size_t)n * Dn + k0 + ((us ^ (n & 7)) * 8);
      gl_lds16(gsrc, &Bs[(i * 512 + wid * 64) * 8]);
    }
    __syncthreads();  // full drain: As + Bs visible to all waves
    // prefetch next A-tile: in flight across the MFMA phase and the raw barrier
    {
      const int k1 = (k0 + 64 < Dn) ? k0 + 64 : k0;
      fa = *(const float4*)(aptr + k1);
    }
#pragma unroll
    for (int kc = 0; kc < 2; ++kc) {
      bf16x8 af[2], bfr[3];
#pragma unroll
      for (int mi = 0; mi < 2; ++mi) {
        const int row = mi * 16 + l15;
        af[mi] = *(const bf16x8*)(&As[row * 64 + (((kc * 4 + g) ^ (row & 7)) * 8)]);
      }
#pragma unroll
      for (int ni = 0; ni < 3; ++ni) {
        const int n = wid * 48 + ni * 16 + l15;
        bfr[ni] = *(const bf16x8*)(&Bs[n * 64 + (((kc * 4 + g) ^ (n & 7)) * 8)]);
      }
#pragma unroll
      for (int mi = 0; mi < 2; ++mi)
#pragma unroll
        for (int ni = 0; ni < 3; ++ni)
          acc[mi][ni] = __builtin_amdgcn_mfma_f32_16x16x32_bf16(af[mi], bfr[ni], acc[mi][ni], 0, 0, 0);
    }
    // RAW barrier: reads of As/Bs are complete (data-dep drained before MFMA issue);
    // no vmcnt drain so the A-prefetch stays in flight.
    __builtin_amdgcn_s_barrier();
  }
  // C-write: n = wid*48 + ni*16 + l15; each (wid,ni) span lies in exactly one of q/k/v
#pragma unroll
  for (int mi = 0; mi < 2; ++mi)
#pragma unroll
    for (int ni = 0; ni < 3; ++ni) {
      const int nb = wid * 48 + ni * 16;
      const int w = nb >> 7;
      u16* dst = (w == 0) ? qb : ((w == 1) ? kb : vb);
      const int h = (nb & 127) + l15;
#pragma unroll
      for (int r = 0; r < 4; ++r)
        dst[(size_t)(m0 + mi * 16 + g4 + r) * Hn + h] = bf16u(acc[mi][ni][r]);
    }
}

// ---------------- V transpose: vb[b][t][h] -> vt[b][h][t] ----------------
__global__ __launch_bounds__(256) void transpose_v_kernel(
    const u16* __restrict__ vb, u16* __restrict__ vt) {
  __shared__ u16 tile[64 * 64];
  const int bid = blockIdx.x;  // 512 = 8b * 32tt * 2hh
  const int b = bid >> 6;
  const int rem = bid & 63;
  const int t0 = (rem >> 1) * 64, h0 = (rem & 1) * 64;
  const int tid = threadIdx.x;
  {
    const int r = tid >> 2, cq = tid & 3;
    const u16* src = vb + (size_t)(b * Tn + t0 + r) * Hn + h0 + cq * 16;
#pragma unroll
    for (int s = 0; s < 2; ++s) {
      u16x8 v = *(const u16x8*)(src + s * 8);
      const int u = cq * 2 + s;
      *(u16x8*)(&tile[r * 64 + (u ^ (r & 7)) * 8]) = v;
    }
  }
  __syncthreads();
  {
    const int hr = tid >> 2, tg = tid & 3;
    u16 outv[16];
#pragma unroll
    for (int j = 0; j < 16; ++j) {
      const int tl = tg * 16 + j;
      outv[j] = tile[tl * 64 + (((hr >> 3) ^ (tl & 7)) * 8) + (hr & 7)];
    }
    u16* dstp = vt + (size_t)(b * Hn + h0 + hr) * Tn + t0 + tg * 16;
    *(u16x8*)(dstp) = *(const u16x8*)(&outv[0]);
    *(u16x8*)(dstp + 8) = *(const u16x8*)(&outv[8]);
  }
}

// ---------------- flash attention: 64 q-rows/block, 4 waves (16 rows each), ----------------
// KV tiles double-buffered in LDS shared by all waves; 2 interleaved KV-halves per q-block;
// partials (o bf16, m, l) written per half; merged by merge_kernel.
__global__ __launch_bounds__(256, 2) void attention_kernel(
    const u16* __restrict__ qb, const u16* __restrict__ kb,
    const u16* __restrict__ vt, u16* __restrict__ po,
    float* __restrict__ pm, float* __restrict__ pl) {
  __shared__ u16 Ks[2][64 * 128];  // K tile [row][128], 16B units XOR(row&15)  (32 KB)
  __shared__ u16 Vs[2][128 * 64];  // V^T tile [h][64], 16B units XOR(h&7)      (32 KB)
  __shared__ u16 Pb[4][16 * 64];   // per-wave P round-trip, XOR-swizzled       (8 KB)

  const int bid = blockIdx.x;  // 512 = 8 batches (bid&7 -> XCD) * 32 qblk * 2 halves
  const int b = bid & 7;
  const int rest = bid >> 3;
  const int s = rest & 1;
  const int kk = rest >> 1;  // 0..31
  const int qblk = (kk & 1) ? (kk >> 1) : (31 - (kk >> 1));  // heavy/light pairing
  const int qb0 = qblk * 64;

  const int tid = threadIdx.x;
  const int wid = tid >> 6;
  const int lane = tid & 63;
  const int l15 = lane & 15;
  const int g = lane >> 4;
  const int g4 = g * 4;
  const int t0w = qb0 + wid * 16;  // this wave's first q row

  const u16* qB = qb + (size_t)b * Tn * Hn;
  const u16* kB = kb + (size_t)b * Tn * Hn;
  const u16* vB = vt + (size_t)b * Hn * Tn;

  bf16x8 qf[4];
#pragma unroll
  for (int kc = 0; kc < 4; ++kc)
    qf[kc] = *(const bf16x8*)(qB + (size_t)(t0w + l15) * Hn + kc * 32 + g * 8);

  const f32x4 fz = {0.f, 0.f, 0.f, 0.f};
  f32x4 o[8];
#pragma unroll
  for (int hc = 0; hc < 8; ++hc) o[hc] = fz;
  float m[4], lsum[4];
#pragma unroll
  for (int r = 0; r < 4; ++r) { m[r] = -__builtin_inff(); lsum[r] = 0.f; }

  u16* P = &Pb[wid][0];
  const int ntiles = (qblk >= s) ? ((qblk - s) >> 1) + 1 : 0;

  // ---- staging helper (block-wide): K tile 1024 units, V tile 1024 units ----
  auto stage = [&](int buf, int kv0) {
#pragma unroll
    for (int j = 0; j < 4; ++j) {
      const int U = j * 256 + tid;
      const int row = U >> 4, us = U & 15;
      const u16* gsrc = kB + (size_t)(kv0 + row) * Hn + ((us ^ (row & 15)) * 8);
      gl_lds16(gsrc, &Ks[buf][(j * 256 + wid * 64) * 8]);
    }
#pragma unroll
    for (int j = 0; j < 4; ++j) {
      const int U = j * 256 + tid;
      const int h = U >> 3, us = U & 7;
      const u16* gsrc = vB + (size_t)h * Tn + kv0 + ((us ^ (h & 7)) * 8);
      gl_lds16(gsrc, &Vs[buf][(j * 256 + wid * 64) * 8]);
    }
  };

  if (ntiles > 0) {
    stage(0, s * 64);
    __syncthreads();
    for (int i = 0; i < ntiles; ++i) {
      const int cur = i & 1;
      if (i + 1 < ntiles) stage(cur ^ 1, (s + 2 * (i + 1)) * 64);
      const int kv0 = (s + 2 * i) * 64;
      const u16* Kl = &Ks[cur][0];
      const u16* Vl = &Vs[cur][0];

      f32x4 S[4];
#pragma unroll
      for (int cn = 0; cn < 4; ++cn) S[cn] = fz;
#pragma unroll
      for (int cn = 0; cn < 4; ++cn) {
#pragma unroll
        for (int kc = 0; kc < 4; ++kc) {
          const int row = cn * 16 + l15;
          const int unit = (kc * 4 + g) ^ (row & 15);
          const bf16x8 kf = *(const bf16x8*)(&Kl[row * 128 + unit * 8]);
          S[cn] = __builtin_amdgcn_mfma_f32_16x16x32_bf16(qf[kc], kf, S[cn], 0, 0, 0);
        }
      }
      if (kv0 + 63 > t0w) {  // causal mask (only the diagonal tile)
#pragma unroll
        for (int cn = 0; cn < 4; ++cn) {
          const int kv = kv0 + cn * 16 + l15;
#pragma unroll
          for (int r = 0; r < 4; ++r)
            if (kv > t0w + g4 + r) S[cn][r] = -__builtin_inff();
        }
      }
      // wave-parallel online softmax (rows live in 16-lane groups)
      float mloc[4];
#pragma unroll
      for (int r = 0; r < 4; ++r)
        mloc[r] = fmaxf(fmaxf(S[0][r], S[1][r]), fmaxf(S[2][r], S[3][r]));
#pragma unroll
      for (int st = 1; st <= 8; st <<= 1)
#pragma unroll
        for (int r = 0; r < 4; ++r)
          mloc[r] = fmaxf(mloc[r], __shfl_xor(mloc[r], st, 64));
      float sc[4], mnew[4];
#pragma unroll
      for (int r = 0; r < 4; ++r) {
        mnew[r] = fmaxf(m[r], mloc[r]);
        sc[r] = __expf(m[r] - mnew[r]);
        m[r] = mnew[r];
      }
      float psum[4] = {0.f, 0.f, 0.f, 0.f};
#pragma unroll
      for (int cn = 0; cn < 4; ++cn)
#pragma unroll
        for (int r = 0; r < 4; ++r) {
          const float p = __expf(S[cn][r] - mnew[r]);
          S[cn][r] = p;
          psum[r] += p;
        }
#pragma unroll
      for (int st = 1; st <= 8; st <<= 1)
#pragma unroll
        for (int r = 0; r < 4; ++r) psum[r] += __shfl_xor(psum[r], st, 64);
#pragma unroll
      for (int r = 0; r < 4; ++r) lsum[r] = lsum[r] * sc[r] + psum[r];
#pragma unroll
      for (int hc = 0; hc < 8; ++hc)
#pragma unroll
        for (int r = 0; r < 4; ++r) o[hc][r] *= sc[r];
      // P: C-layout -> A-frag layout via per-wave swizzled LDS round-trip (wave-local sync).
      asm volatile("s_waitcnt lgkmcnt(0)" ::: "memory");  // prior pf reads done before overwrite
#pragma unroll
      for (int cn = 0; cn < 4; ++cn)
#pragma unroll
        for (int r = 0; r < 4; ++r) {
          const int q = g4 + r;
          const int col = cn * 16 + l15;
          P[q * 64 + (col ^ ((q & 7) << 3))] = bf16u(S[cn][r]);
        }
      asm volatile("s_waitcnt lgkmcnt(0)" ::: "memory");
      bf16x8 pf[2];
#pragma unroll
      for (int kvc = 0; kvc < 2; ++kvc)
        pf[kvc] = *(const bf16x8*)(&P[l15 * 64 + (((kvc * 32 + g * 8) ^ ((l15 & 7) << 3)))]);
#pragma unroll
      for (int hc = 0; hc < 8; ++hc) {
#pragma unroll
        for (int kvc = 0; kvc < 2; ++kvc) {
          const int h = hc * 16 + l15;
          const int unit = (kvc * 4 + g) ^ (h & 7);
          const bf16x8 vf = *(const bf16x8*)(&Vl[h * 64 + unit * 8]);
          o[hc] = __builtin_amdgcn_mfma_f32_16x16x32_bf16(pf[kvc], vf, o[hc], 0, 0, 0);
        }
      }
      __syncthreads();  // staged(next) complete + all reads of cur done
    }
  }

  // ---- write partials (unconditional; empty half writes m=-inf, l=0, o=0) ----
  u16* poS = po + ((size_t)(s * 8 + b) * Tn + t0w) * Hn;
#pragma unroll
  for (int hc = 0; hc < 8; ++hc)
#pragma unroll
    for (int r = 0; r < 4; ++r)
      poS[(size_t)(g4 + r) * Hn + hc * 16 + l15] = bf16u(o[hc][r]);
  if (l15 == 0) {
#pragma unroll
    for (int r = 0; r < 4; ++r) {
      pm[(size_t)(s * 8 + b) * Tn + t0w + g4 + r] = m[r];
      pl[(size_t)(s * 8 + b) * Tn + t0w + g4 + r] = lsum[r];
    }
  }
}

// ---------------- merge the two KV-half partials: out = (e0*o0 + e1*o1) / L ----------------
__global__ __launch_bounds__(256) void merge_kernel(
    const u16* __restrict__ po, const float* __restrict__ pm,
    const float* __restrict__ pl, float* __restrict__ out) {
  const int tid = threadIdx.x;
  const int row = blockIdx.x * 8 + (tid >> 5);  // 0..16383
  const int h0 = (tid & 31) * 4;
  const float m0 = pm[row], m1 = pm[8 * Tn + row];
  const float l0 = pl[row], l1 = pl[8 * Tn + row];
  const float M = fmaxf(m0, m1);
  const float e0 = __expf(m0 - M), e1 = __expf(m1 - M);
  const float invL = 1.0f / (e0 * l0 + e1 * l1);
  const ushort4 a = *(const ushort4*)(po + (size_t)row * Hn + h0);
  const ushort4 c = *(const ushort4*)(po + (size_t)(8 * Tn + row) * Hn + h0);
  float4 r;
  r.x = (e0 * u16f(a.x) + e1 * u16f(c.x)) * invL;
  r.y = (e0 * u16f(a.y) + e1 * u16f(c.y)) * invL;
  r.z = (e0 * u16f(a.z) + e1 * u16f(c.z)) * invL;
  r.w = (e0 * u16f(a.w) + e1 * u16f(c.w)) * invL;
  *(float4*)(out + (size_t)row * Hn + h0) = r;
}

extern "C" void kernel_launch(void* const* d_in, const int* in_sizes, int n_in,
                              void* d_out, int out_size, void* d_ws, size_t ws_size,
                              hipStream_t stream) {
  const float* x  = (const float*)d_in[0];
  const float* Wq = (const float*)d_in[1];
  const float* Wk = (const float*)d_in[2];
  const float* Wv = (const float*)d_in[3];
  float* out = (float*)d_out;
  char* ws = (char*)d_ws;
  // ws layout (~25.5 MB total):
  u16* WT = (u16*)(ws);                    // 768 KB: bf16 W^T [384][1024]
  u16* qb = (u16*)(ws + (1u << 20));       // 4 MB
  u16* kb = (u16*)(ws + (5u << 20));       // 4 MB
  u16* vb = (u16*)(ws + (9u << 20));       // 4 MB
  u16* vt = (u16*)(ws + (13u << 20));      // 4 MB: V^T [b][h][t]
  u16* po = (u16*)(ws + (17u << 20));      // 8 MB: partial O bf16 [2][8][2048][128]
  float* pm = (float*)(ws + (25u << 20));            // 128 KB [2][8][2048]
  float* pl = (float*)(ws + (25u << 20) + (1u << 18));  // 128 KB

  convert_w_kernel<<<384, 256, 0, stream>>>(Wq, Wk, Wv, WT);
  qkv_gemm_kernel<<<512, 512, 0, stream>>>(x, WT, qb, kb, vb);
  transpose_v_kernel<<<512, 256, 0, stream>>>(vb, vt);
  attention_kernel<<<512, 256, 0, stream>>>(qb, kb, vt, po, pm, pl);
  merge_kernel<<<2048, 256, 0, stream>>>(po, pm, pl, out);
}

// Round 6
// 159.460 us; speedup vs baseline: 1.6926x; 1.0373x over previous
//
#include <hip/hip_runtime.h>
#include <hip/hip_bf16.h>
#include <stdint.h>

typedef __bf16 bf16x8 __attribute__((ext_vector_type(8)));
typedef float f32x4 __attribute__((ext_vector_type(4)));
typedef unsigned short u16;
typedef u16 u16x8 __attribute__((ext_vector_type(8)));

#define GAS __attribute__((address_space(1)))
#define LAS __attribute__((address_space(3)))

static constexpr int Tn = 2048;
static constexpr int Dn = 1024;
static constexpr int Hn = 128;

__device__ __forceinline__ u16 bf16u(float f) {
  __bf16 h = (__bf16)f;
  return __builtin_bit_cast(u16, h);
}
__device__ __forceinline__ float u16f(u16 u) {
  uint32_t t = (uint32_t)u << 16;
  return __builtin_bit_cast(float, t);
}

__device__ __forceinline__ void gl_lds16(const void* g, void* l) {
  __builtin_amdgcn_global_load_lds((GAS void*)g, (LAS void*)l, 16, 0, 0);
}

// ---------------- convert + transpose weights: WT[w][h][d] bf16, Wq pre-scaled ----------------
__global__ __launch_bounds__(256) void convert_w_kernel(
    const float* __restrict__ Wq, const float* __restrict__ Wk,
    const float* __restrict__ Wv, u16* __restrict__ WT) {
  const int bid = blockIdx.x;  // 384 = 3*128
  const int w = bid >> 7;
  const int h = bid & 127;
  const float* src = (w == 0) ? Wq : ((w == 1) ? Wk : Wv);
  const float scale = (w == 0) ? 0.08838834764831845f : 1.0f;  // 1/sqrt(128) folded into Wq
  const int d0 = threadIdx.x * 4;
  ushort4 v;
  v.x = bf16u(src[(size_t)(d0 + 0) * Hn + h] * scale);
  v.y = bf16u(src[(size_t)(d0 + 1) * Hn + h] * scale);
  v.z = bf16u(src[(size_t)(d0 + 2) * Hn + h] * scale);
  v.w = bf16u(src[(size_t)(d0 + 3) * Hn + h] * scale);
  *(ushort4*)(&WT[(size_t)(w * Hn + h) * Dn + d0]) = v;
}

// ---------------- fused QKV GEMM: [16384x1024] x [1024x384] (q|k|v), x read ONCE ----------------
// BM=64, BN=384, BK=64, double-buffered 2-phase pipeline; 8 waves, wave tile 64x48.
// V output written directly transposed into vt[b][h][t] (contiguous ushort4 stores).
__global__ __launch_bounds__(512, 2) void qkv_gemm_kernel(
    const float* __restrict__ x, const u16* __restrict__ WT,
    u16* __restrict__ qb, u16* __restrict__ kb, u16* __restrict__ vt) {
  __shared__ u16 As[2][64 * 64];   // [row][64 k] bf16, XOR-swizzled 16B units (16 KB)
  __shared__ u16 Bs[2][384 * 64];  // [n][64 k] bf16, XOR-swizzled via pre-swizzled src (96 KB)
  const int m0 = blockIdx.x * 64;
  const int tid = threadIdx.x;
  const int lane = tid & 63;
  const int wid = tid >> 6;
  const int l15 = lane & 15;
  const int g = lane >> 4;
  const int g4 = g * 4;

  const f32x4 fz = {0.f, 0.f, 0.f, 0.f};
  f32x4 acc[4][3];
#pragma unroll
  for (int i = 0; i < 4; ++i)
#pragma unroll
    for (int j = 0; j < 3; ++j) acc[i][j] = fz;

  // A-stage: 64 rows x 16 float4-units = 1024 units; 512 threads x 2 passes
  const int row0 = tid >> 4;        // rows 0..31
  const int row1 = row0 + 32;       // rows 32..63
  const int c16 = tid & 15;
  const int slot0 = (c16 >> 1) ^ (row0 & 7);
  const int slot1 = (c16 >> 1) ^ (row1 & 7);
  const int ahalf = c16 & 1;
  const float* a0p = x + (size_t)(m0 + row0) * Dn + c16 * 4;
  const float* a1p = x + (size_t)(m0 + row1) * Dn + c16 * 4;

  auto stageB = [&](int buf, int k0) {
#pragma unroll
    for (int i = 0; i < 6; ++i) {
      const int s = i * 512 + tid;
      const int n = s >> 3;
      const int us = s & 7;
      const u16* gsrc = WT + (size_t)n * Dn + k0 + ((us ^ (n & 7)) * 8);
      gl_lds16(gsrc, &Bs[buf][(i * 512 + wid * 64) * 8]);
    }
  };
  auto writeA = [&](int buf, float4 f0, float4 f1) {
    ushort4 p0, p1;
    p0.x = bf16u(f0.x); p0.y = bf16u(f0.y); p0.z = bf16u(f0.z); p0.w = bf16u(f0.w);
    p1.x = bf16u(f1.x); p1.y = bf16u(f1.y); p1.z = bf16u(f1.z); p1.w = bf16u(f1.w);
    *(ushort4*)(&As[buf][row0 * 64 + slot0 * 8 + ahalf * 4]) = p0;
    *(ushort4*)(&As[buf][row1 * 64 + slot1 * 8 + ahalf * 4]) = p1;
  };

  // prologue: stage k=0 into buffer 0
  {
    const float4 f0 = *(const float4*)(a0p);
    const float4 f1 = *(const float4*)(a1p);
    writeA(0, f0, f1);
    stageB(0, 0);
  }
  int cur = 0;
  for (int k = 0; k < 16; ++k) {
    __syncthreads();  // stage(k) complete & visible
    float4 n0, n1;
    if (k < 15) {  // issue stage(k+1): loads fly across compute(k)
      n0 = *(const float4*)(a0p + (k + 1) * 64);
      n1 = *(const float4*)(a1p + (k + 1) * 64);
      stageB(cur ^ 1, (k + 1) * 64);
    }
#pragma unroll
    for (int kc = 0; kc < 2; ++kc) {
      bf16x8 af[4], bfr[3];
#pragma unroll
      for (int mi = 0; mi < 4; ++mi) {
        const int row = mi * 16 + l15;
        af[mi] = *(const bf16x8*)(&As[cur][row * 64 + (((kc * 4 + g) ^ (row & 7)) * 8)]);
      }
#pragma unroll
      for (int ni = 0; ni < 3; ++ni) {
        const int n = wid * 48 + ni * 16 + l15;
        bfr[ni] = *(const bf16x8*)(&Bs[cur][n * 64 + (((kc * 4 + g) ^ (n & 7)) * 8)]);
      }
#pragma unroll
      for (int mi = 0; mi < 4; ++mi)
#pragma unroll
        for (int ni = 0; ni < 3; ++ni)
          acc[mi][ni] = __builtin_amdgcn_mfma_f32_16x16x32_bf16(af[mi], bfr[ni], acc[mi][ni], 0, 0, 0);
    }
    if (k < 15) writeA(cur ^ 1, n0, n1);  // A(k+1) -> LDS; visible after next barrier
    cur ^= 1;
  }
  // C-write: cols nb = wid*48 + ni*16 (never crosses a 128 boundary within a 16-span)
#pragma unroll
  for (int mi = 0; mi < 4; ++mi)
#pragma unroll
    for (int ni = 0; ni < 3; ++ni) {
      const int nb = wid * 48 + ni * 16;
      const int w = nb >> 7;
      const int hcol = (nb & 127) + l15;
      const int grow0 = m0 + mi * 16 + g4;
      if (w == 2) {  // V: write transposed, 4 consecutive t -> one ushort4
        const int b = grow0 >> 11;
        const int tl = grow0 & 2047;
        ushort4 vv;
        vv.x = bf16u(acc[mi][ni][0]); vv.y = bf16u(acc[mi][ni][1]);
        vv.z = bf16u(acc[mi][ni][2]); vv.w = bf16u(acc[mi][ni][3]);
        *(ushort4*)(&vt[((size_t)(b * Hn + hcol)) * Tn + tl]) = vv;
      } else {
        u16* dst = (w == 0) ? qb : kb;
#pragma unroll
        for (int r = 0; r < 4; ++r)
          dst[(size_t)(grow0 + r) * Hn + hcol] = bf16u(acc[mi][ni][r]);
      }
    }
}

// ---------------- flash attention: 64 q-rows/block, 4 waves (16 rows each), ----------------
// KV tiles double-buffered in LDS shared by all waves; 2 interleaved KV-halves per q-block;
// partials (o bf16, m, l) written per half; merged by merge_kernel.
__global__ __launch_bounds__(256, 2) void attention_kernel(
    const u16* __restrict__ qb, const u16* __restrict__ kb,
    const u16* __restrict__ vt, u16* __restrict__ po,
    float* __restrict__ pm, float* __restrict__ pl) {
  __shared__ u16 Ks[2][64 * 128];  // K tile [row][128], 16B units XOR(row&15)  (32 KB)
  __shared__ u16 Vs[2][128 * 64];  // V^T tile [h][64], 16B units XOR(h&7)      (32 KB)
  __shared__ u16 Pb[4][16 * 64];   // per-wave P round-trip, XOR-swizzled       (8 KB)

  const int bid = blockIdx.x;  // 512 = 8 batches (bid&7 -> XCD) * 32 qblk * 2 halves
  const int b = bid & 7;
  const int rest = bid >> 3;
  const int s = rest & 1;
  const int kk = rest >> 1;  // 0..31
  const int qblk = (kk & 1) ? (kk >> 1) : (31 - (kk >> 1));  // heavy/light pairing
  const int qb0 = qblk * 64;

  const int tid = threadIdx.x;
  const int wid = tid >> 6;
  const int lane = tid & 63;
  const int l15 = lane & 15;
  const int g = lane >> 4;
  const int g4 = g * 4;
  const int t0w = qb0 + wid * 16;  // this wave's first q row

  const u16* qB = qb + (size_t)b * Tn * Hn;
  const u16* kB = kb + (size_t)b * Tn * Hn;
  const u16* vB = vt + (size_t)b * Hn * Tn;

  bf16x8 qf[4];
#pragma unroll
  for (int kc = 0; kc < 4; ++kc)
    qf[kc] = *(const bf16x8*)(qB + (size_t)(t0w + l15) * Hn + kc * 32 + g * 8);

  const f32x4 fz = {0.f, 0.f, 0.f, 0.f};
  f32x4 o[8];
#pragma unroll
  for (int hc = 0; hc < 8; ++hc) o[hc] = fz;
  float m[4], lsum[4];
#pragma unroll
  for (int r = 0; r < 4; ++r) { m[r] = -__builtin_inff(); lsum[r] = 0.f; }

  u16* P = &Pb[wid][0];
  const int ntiles = (qblk >= s) ? ((qblk - s) >> 1) + 1 : 0;

  // ---- staging helper (block-wide): K tile 1024 units, V tile 1024 units ----
  auto stage = [&](int buf, int kv0) {
#pragma unroll
    for (int j = 0; j < 4; ++j) {
      const int U = j * 256 + tid;
      const int row = U >> 4, us = U & 15;
      const u16* gsrc = kB + (size_t)(kv0 + row) * Hn + ((us ^ (row & 15)) * 8);
      gl_lds16(gsrc, &Ks[buf][(j * 256 + wid * 64) * 8]);
    }
#pragma unroll
    for (int j = 0; j < 4; ++j) {
      const int U = j * 256 + tid;
      const int h = U >> 3, us = U & 7;
      const u16* gsrc = vB + (size_t)h * Tn + kv0 + ((us ^ (h & 7)) * 8);
      gl_lds16(gsrc, &Vs[buf][(j * 256 + wid * 64) * 8]);
    }
  };

  if (ntiles > 0) {
    stage(0, s * 64);
    __syncthreads();
    for (int i = 0; i < ntiles; ++i) {
      const int cur = i & 1;
      if (i + 1 < ntiles) stage(cur ^ 1, (s + 2 * (i + 1)) * 64);
      const int kv0 = (s + 2 * i) * 64;
      const u16* Kl = &Ks[cur][0];
      const u16* Vl = &Vs[cur][0];

      f32x4 S[4];
#pragma unroll
      for (int cn = 0; cn < 4; ++cn) S[cn] = fz;
#pragma unroll
      for (int cn = 0; cn < 4; ++cn) {
#pragma unroll
        for (int kc = 0; kc < 4; ++kc) {
          const int row = cn * 16 + l15;
          const int unit = (kc * 4 + g) ^ (row & 15);
          const bf16x8 kf = *(const bf16x8*)(&Kl[row * 128 + unit * 8]);
          S[cn] = __builtin_amdgcn_mfma_f32_16x16x32_bf16(qf[kc], kf, S[cn], 0, 0, 0);
        }
      }
      if (kv0 + 63 > t0w) {  // causal mask (only the diagonal tile)
#pragma unroll
        for (int cn = 0; cn < 4; ++cn) {
          const int kv = kv0 + cn * 16 + l15;
#pragma unroll
          for (int r = 0; r < 4; ++r)
            if (kv > t0w + g4 + r) S[cn][r] = -__builtin_inff();
        }
      }
      // wave-parallel online softmax (rows live in 16-lane groups)
      float mloc[4];
#pragma unroll
      for (int r = 0; r < 4; ++r)
        mloc[r] = fmaxf(fmaxf(S[0][r], S[1][r]), fmaxf(S[2][r], S[3][r]));
#pragma unroll
      for (int st = 1; st <= 8; st <<= 1)
#pragma unroll
        for (int r = 0; r < 4; ++r)
          mloc[r] = fmaxf(mloc[r], __shfl_xor(mloc[r], st, 64));
      float sc[4], mnew[4];
#pragma unroll
      for (int r = 0; r < 4; ++r) {
        mnew[r] = fmaxf(m[r], mloc[r]);
        sc[r] = __expf(m[r] - mnew[r]);
        m[r] = mnew[r];
      }
      float psum[4] = {0.f, 0.f, 0.f, 0.f};
#pragma unroll
      for (int cn = 0; cn < 4; ++cn)
#pragma unroll
        for (int r = 0; r < 4; ++r) {
          const float p = __expf(S[cn][r] - mnew[r]);
          S[cn][r] = p;
          psum[r] += p;
        }
#pragma unroll
      for (int st = 1; st <= 8; st <<= 1)
#pragma unroll
        for (int r = 0; r < 4; ++r) psum[r] += __shfl_xor(psum[r], st, 64);
#pragma unroll
      for (int r = 0; r < 4; ++r) lsum[r] = lsum[r] * sc[r] + psum[r];
#pragma unroll
      for (int hc = 0; hc < 8; ++hc)
#pragma unroll
        for (int r = 0; r < 4; ++r) o[hc][r] *= sc[r];
      // P: C-layout -> A-frag layout via per-wave swizzled LDS round-trip (wave-local sync).
      asm volatile("s_waitcnt lgkmcnt(0)" ::: "memory");  // prior pf reads done before overwrite
#pragma unroll
      for (int cn = 0; cn < 4; ++cn)
#pragma unroll
        for (int r = 0; r < 4; ++r) {
          const int q = g4 + r;
          const int col = cn * 16 + l15;
          P[q * 64 + (col ^ ((q & 7) << 3))] = bf16u(S[cn][r]);
        }
      asm volatile("s_waitcnt lgkmcnt(0)" ::: "memory");
      bf16x8 pf[2];
#pragma unroll
      for (int kvc = 0; kvc < 2; ++kvc)
        pf[kvc] = *(const bf16x8*)(&P[l15 * 64 + (((kvc * 32 + g * 8) ^ ((l15 & 7) << 3)))]);
#pragma unroll
      for (int hc = 0; hc < 8; ++hc) {
#pragma unroll
        for (int kvc = 0; kvc < 2; ++kvc) {
          const int h = hc * 16 + l15;
          const int unit = (kvc * 4 + g) ^ (h & 7);
          const bf16x8 vf = *(const bf16x8*)(&Vl[h * 64 + unit * 8]);
          o[hc] = __builtin_amdgcn_mfma_f32_16x16x32_bf16(pf[kvc], vf, o[hc], 0, 0, 0);
        }
      }
      __syncthreads();  // staged(next) complete + all reads of cur done
    }
  }

  // ---- write partials (unconditional; empty half writes m=-inf, l=0, o=0) ----
  u16* poS = po + ((size_t)(s * 8 + b) * Tn + t0w) * Hn;
#pragma unroll
  for (int hc = 0; hc < 8; ++hc)
#pragma unroll
    for (int r = 0; r < 4; ++r)
      poS[(size_t)(g4 + r) * Hn + hc * 16 + l15] = bf16u(o[hc][r]);
  if (l15 == 0) {
#pragma unroll
    for (int r = 0; r < 4; ++r) {
      pm[(size_t)(s * 8 + b) * Tn + t0w + g4 + r] = m[r];
      pl[(size_t)(s * 8 + b) * Tn + t0w + g4 + r] = lsum[r];
    }
  }
}

// ---------------- merge the two KV-half partials: out = (e0*o0 + e1*o1) / L ----------------
__global__ __launch_bounds__(256) void merge_kernel(
    const u16* __restrict__ po, const float* __restrict__ pm,
    const float* __restrict__ pl, float* __restrict__ out) {
  const int tid = threadIdx.x;
  const int row = blockIdx.x * 8 + (tid >> 5);  // 0..16383
  const int h0 = (tid & 31) * 4;
  const float m0 = pm[row], m1 = pm[8 * Tn + row];
  const float l0 = pl[row], l1 = pl[8 * Tn + row];
  const float M = fmaxf(m0, m1);
  const float e0 = __expf(m0 - M), e1 = __expf(m1 - M);
  const float invL = 1.0f / (e0 * l0 + e1 * l1);
  const ushort4 a = *(const ushort4*)(po + (size_t)row * Hn + h0);
  const ushort4 c = *(const ushort4*)(po + (size_t)(8 * Tn + row) * Hn + h0);
  float4 r;
  r.x = (e0 * u16f(a.x) + e1 * u16f(c.x)) * invL;
  r.y = (e0 * u16f(a.y) + e1 * u16f(c.y)) * invL;
  r.z = (e0 * u16f(a.z) + e1 * u16f(c.z)) * invL;
  r.w = (e0 * u16f(a.w) + e1 * u16f(c.w)) * invL;
  *(float4*)(out + (size_t)row * Hn + h0) = r;
}

extern "C" void kernel_launch(void* const* d_in, const int* in_sizes, int n_in,
                              void* d_out, int out_size, void* d_ws, size_t ws_size,
                              hipStream_t stream) {
  const float* x  = (const float*)d_in[0];
  const float* Wq = (const float*)d_in[1];
  const float* Wk = (const float*)d_in[2];
  const float* Wv = (const float*)d_in[3];
  float* out = (float*)d_out;
  char* ws = (char*)d_ws;
  // ws layout (~22.5 MB total):
  u16* WT = (u16*)(ws);                    // 768 KB: bf16 W^T [384][1024]
  u16* qb = (u16*)(ws + (1u << 20));       // 4 MB
  u16* kb = (u16*)(ws + (5u << 20));       // 4 MB
  u16* vt = (u16*)(ws + (9u << 20));       // 4 MB: V^T [b][h][t] (written by GEMM)
  u16* po = (u16*)(ws + (13u << 20));      // 8 MB: partial O bf16 [2][8][2048][128]
  float* pm = (float*)(ws + (22u << 20));               // 128 KB [2][8][2048]
  float* pl = (float*)(ws + (22u << 20) + (1u << 18));  // 128 KB

  convert_w_kernel<<<384, 256, 0, stream>>>(Wq, Wk, Wv, WT);
  qkv_gemm_kernel<<<256, 512, 0, stream>>>(x, WT, qb, kb, vt);
  attention_kernel<<<512, 256, 0, stream>>>(qb, kb, vt, po, pm, pl);
  merge_kernel<<<2048, 256, 0, stream>>>(po, pm, pl, out);
}